// Round 2
// baseline (1558.845 us; speedup 1.0000x reference)
//
#include <hip/hip_runtime.h>
#include <hip/hip_bf16.h>

#define N_ROWS 100000
#define D 256
#define B 512
#define RT 25          // rows per block in fused kernel (100000 = 4000 * 25)
#define PPAD 516       // 512 + 4 pad (multiple of 4 keeps float4 alignment)

__device__ __forceinline__ float lo16(unsigned u) { return __uint_as_float(u << 16); }
__device__ __forceinline__ float hi16(unsigned u) { return __uint_as_float(u & 0xffff0000u); }
__device__ __forceinline__ unsigned short bf16r(float f) {
    unsigned u = __float_as_uint(f);
    unsigned r = (u + 0x7fffu + ((u >> 16) & 1u)) >> 16;   // RNE
    return (unsigned short)r;
}

// ---- dtype-generic accessors (BH = inputs/outputs are bf16; else fp32) ----
template<bool BH>
__device__ __forceinline__ float ldf(const void* p, size_t i) {
    if constexpr (BH) return lo16(((const unsigned short*)p)[i]);
    else              return ((const float*)p)[i];
}
template<bool BH>
__device__ __forceinline__ void ld8(const void* p, size_t i, float* o) {  // i multiple of 8
    if constexpr (BH) {
        uint4 v = *(const uint4*)((const unsigned short*)p + i);
        o[0]=lo16(v.x); o[1]=hi16(v.x); o[2]=lo16(v.y); o[3]=hi16(v.y);
        o[4]=lo16(v.z); o[5]=hi16(v.z); o[6]=lo16(v.w); o[7]=hi16(v.w);
    } else {
        const float4* q = (const float4*)((const float*)p + i);
        float4 a = q[0], b = q[1];
        o[0]=a.x; o[1]=a.y; o[2]=a.z; o[3]=a.w;
        o[4]=b.x; o[5]=b.y; o[6]=b.z; o[7]=b.w;
    }
}
template<bool BH>
__device__ __forceinline__ void stf(void* p, size_t i, float v) {
    if constexpr (BH) ((unsigned short*)p)[i] = bf16r(v);
    else              ((float*)p)[i] = v;
}

// ---------------- Kernel 0: dtype sniff ----------------
// fp32 N(0,1): low 16 bits of each word are uniform mantissa bits -> as-bf16
// exponent > 135 with p=0.47 per word; 128 words => P(all pass) ~ 1e-35.
// bf16 N(0,1): every half has exponent <= ~130 -> always passes.
__global__ void sniff_kernel(const unsigned* __restrict__ h, int* __restrict__ flag) {
    if (threadIdx.x == 0 && blockIdx.x == 0) {
        int bad = 0;
        for (int i = 0; i < 128; ++i) {
            unsigned w = h[i];
            unsigned e0 = (w >> 7)  & 0xffu;
            unsigned e1 = (w >> 23) & 0xffu;
            if (e0 > 135u || e1 > 135u) bad = 1;
        }
        *flag = bad ? 0 : 1;   // 1 = bf16
    }
}

// ---------------- Kernel 1: segment sums (scatter atomics) ----------------
template<bool BH>
__device__ __forceinline__ void seg_body(const void* __restrict__ V, const void* __restrict__ bkp,
                                         float* __restrict__ sums, float* __restrict__ counts,
                                         float* __restrict__ gsum) {
    // index-dtype sniff: int64 vs int32 (deterministic, same answer every block)
    bool is64 = true;
    const long long* b64 = (const long long*)bkp;
    #pragma unroll
    for (int j = 0; j < 16; ++j) {
        long long v = b64[j];
        if (v < 0 || v >= B) is64 = false;
    }
    const int* b32 = (const int*)bkp;
    const int t = threadIdx.x;
    float g = 0.f;
    for (int row = blockIdx.x; row < N_ROWS; row += gridDim.x) {
        int k = is64 ? (int)b64[row] : b32[row];
        float v = ldf<BH>(V, (size_t)row * D + t);
        atomicAdd(&sums[k * D + t], v);
        g += v;
        if (t == 0) atomicAdd(&counts[k], 1.0f);
    }
    atomicAdd(&gsum[t], g);
}
__global__ __launch_bounds__(256) void seg_kernel(const void* V, const void* bk,
                                                  float* sums, float* counts, float* gsum,
                                                  const int* flag) {
    if (*flag) seg_body<true>(V, bk, sums, counts, gsum);
    else       seg_body<false>(V, bk, sums, counts, gsum);
}

// ------- Kernel 2: prototypes + protoW = proto @ W_r^T (interleaved f4 layout) -------
template<bool BH>
__device__ __forceinline__ void proto_body(const float* __restrict__ sums,
                                           const float* __restrict__ counts,
                                           const float* __restrict__ gsum,
                                           const void* __restrict__ W_r,
                                           float* __restrict__ protoWi) {
    __shared__ __align__(16) float proto[D];
    const int b = blockIdx.x, t = threadIdx.x;
    float c = counts[b];
    proto[t] = (c > 0.5f) ? sums[b * D + t] / c : gsum[t] * (1.0f / N_ROWS);
    __syncthreads();
    // protoW[b][t] = sum_k proto[k] * W_r[t][k]
    float acc = 0.f;
    float w[8];
    #pragma unroll
    for (int c8 = 0; c8 < D / 8; ++c8) {
        ld8<BH>(W_r, (size_t)t * D + c8 * 8, w);
        #pragma unroll
        for (int j = 0; j < 8; ++j) acc = fmaf(proto[c8 * 8 + j], w[j], acc);
    }
    // interleaved: protoWi[(b/4)*1024 + t*4 + (b%4)] -> fused reads float4 per 4-bucket chunk
    protoWi[(size_t)(b >> 2) * (D * 4) + t * 4 + (b & 3)] = acc;
}
__global__ __launch_bounds__(256) void proto_kernel(const float* sums, const float* counts,
                                                    const float* gsum, const void* W_r,
                                                    float* protoWi, const int* flag) {
    if (*flag) proto_body<true>(sums, counts, gsum, W_r, protoWi);
    else       proto_body<false>(sums, counts, gsum, W_r, protoWi);
}

// ------- Kernel 3: softmax+entropy -> matvec -> gated add -> LayerNorm -------
template<bool BH>
__device__ __forceinline__ void fused_body(const void* __restrict__ logits,
                                           const void* __restrict__ h_fused,
                                           const float* __restrict__ protoWi,
                                           const void* __restrict__ gamma,
                                           const void* __restrict__ beta,
                                           void* __restrict__ out) {
    __shared__ __align__(16) float p_lds[RT * PPAD];
    __shared__ float gate_lds[RT];
    __shared__ float part1[RT][4];
    __shared__ float part2[RT][4];

    const int t = threadIdx.x;
    const int grp = t >> 3, sub = t & 7;
    const long long base_row = (long long)blockIdx.x * RT;

    // ---- phase 1: softmax + entropy for RT rows, 8 threads per row ----
    if (grp < RT) {
        const long long row = base_row + grp;
        float x[64];
        #pragma unroll
        for (int c = 0; c < 8; ++c)
            ld8<BH>(logits, (size_t)row * B + sub * 64 + c * 8, &x[c * 8]);
        float m = x[0];
        #pragma unroll
        for (int k = 1; k < 64; ++k) m = fmaxf(m, x[k]);
        m = fmaxf(m, __shfl_xor(m, 1));
        m = fmaxf(m, __shfl_xor(m, 2));
        m = fmaxf(m, __shfl_xor(m, 4));
        float S = 0.f;
        #pragma unroll
        for (int k = 0; k < 64; ++k) { x[k] = __expf(x[k] - m); S += x[k]; }
        S += __shfl_xor(S, 1); S += __shfl_xor(S, 2); S += __shfl_xor(S, 4);
        const float inv = 1.0f / S;
        float ent = 0.f;
        #pragma unroll
        for (int k = 0; k < 64; ++k) {
            float p = x[k] * inv;
            ent = fmaf(p, __logf(p + 1e-9f), ent);   // sum p*log(p+1e-9) (negative)
        }
        ent += __shfl_xor(ent, 1); ent += __shfl_xor(ent, 2); ent += __shfl_xor(ent, 4);
        const float gate = -ent * 0.16035674514745464f;  // entropy / ln(512)
        float* prow = &p_lds[grp * PPAD + sub * 64];
        #pragma unroll
        for (int c = 0; c < 16; ++c) {
            *(float4*)&prow[c * 4] = make_float4(x[c * 4 + 0] * inv, x[c * 4 + 1] * inv,
                                                 x[c * 4 + 2] * inv, x[c * 4 + 3] * inv);
        }
        if (sub == 0) {
            gate_lds[grp] = gate;
            stf<BH>(out, (size_t)N_ROWS * D + row, 1.0f - gate);   // confidence
        }
    }
    __syncthreads();

    // ---- phase 2: residual[r][t] = sum_b p[r][b] * protoW[b][t] ----
    float acc[RT];
    #pragma unroll
    for (int r = 0; r < RT; ++r) acc[r] = 0.f;
    const float4* pw4 = (const float4*)protoWi;
    for (int c = 0; c < B / 4; ++c) {
        const float4 w = pw4[c * D + t];   // protoW[4c..4c+3][t], coalesced
        #pragma unroll
        for (int r = 0; r < RT; ++r) {
            const float4 pv = *(const float4*)&p_lds[r * PPAD + c * 4];  // broadcast
            acc[r] = fmaf(pv.x, w.x, acc[r]);
            acc[r] = fmaf(pv.y, w.y, acc[r]);
            acc[r] = fmaf(pv.z, w.z, acc[r]);
            acc[r] = fmaf(pv.w, w.w, acc[r]);
        }
    }

    // ---- phase 3: gated add + LayerNorm ----
    const float g  = ldf<BH>(gamma, t);
    const float bt = ldf<BH>(beta, t);
    const int wv = t >> 6, ln = t & 63;
    #pragma unroll
    for (int r = 0; r < RT; ++r) {
        const long long row = base_row + r;
        float hv = fmaf(gate_lds[r], acc[r], ldf<BH>(h_fused, (size_t)row * D + t));
        acc[r] = hv;
        float s1 = hv, s2 = hv * hv;
        #pragma unroll
        for (int o = 32; o > 0; o >>= 1) { s1 += __shfl_xor(s1, o); s2 += __shfl_xor(s2, o); }
        if (ln == 0) { part1[r][wv] = s1; part2[r][wv] = s2; }
    }
    __syncthreads();
    #pragma unroll
    for (int r = 0; r < RT; ++r) {
        float sum = part1[r][0] + part1[r][1] + part1[r][2] + part1[r][3];
        float sq  = part2[r][0] + part2[r][1] + part2[r][2] + part2[r][3];
        float mean = sum * (1.0f / D);
        float var  = fmaf(-mean, mean, sq * (1.0f / D));
        float rstd = rsqrtf(var + 1e-5f);
        const long long row = base_row + r;
        stf<BH>(out, (size_t)row * D + t, fmaf((acc[r] - mean) * rstd, g, bt));
    }
}
__global__ __launch_bounds__(256) void fused_kernel(const void* logits, const void* h_fused,
                                                    const float* protoWi, const void* gamma,
                                                    const void* beta, void* out, const int* flag) {
    if (*flag) fused_body<true>(logits, h_fused, protoWi, gamma, beta, out);
    else       fused_body<false>(logits, h_fused, protoWi, gamma, beta, out);
}

extern "C" void kernel_launch(void* const* d_in, const int* in_sizes, int n_in,
                              void* d_out, int out_size, void* d_ws, size_t ws_size,
                              hipStream_t stream) {
    const void* h_fused = d_in[0];
    const void* V       = d_in[1];
    const void* logits  = d_in[2];
    const void* bk      = d_in[3];
    const void* W_r     = d_in[4];
    const void* gamma   = d_in[5];
    const void* beta    = d_in[6];

    float* ws      = (float*)d_ws;
    float* sums    = ws;                 // B*D   = 131072 f32
    float* counts  = ws + 131072;        // B     = 512
    float* gsum    = ws + 131584;        // D     = 256
    float* protoWi = ws + 131840;        // B*D   = 131072 (16B-aligned)
    int*   flag    = (int*)(ws + 262912);

    hipMemsetAsync(d_ws, 0, (size_t)131840 * sizeof(float), stream);
    sniff_kernel<<<1, 64, 0, stream>>>((const unsigned*)h_fused, flag);
    seg_kernel<<<1024, 256, 0, stream>>>(V, bk, sums, counts, gsum, flag);
    proto_kernel<<<B, 256, 0, stream>>>(sums, counts, gsum, W_r, protoWi, flag);
    fused_kernel<<<N_ROWS / RT, 256, 0, stream>>>(logits, h_fused, protoWi, gamma, beta, d_out, flag);
}